// Round 8
// baseline (44.073 us; speedup 1.0000x reference)
//
#include <hip/hip_runtime.h>
#include <math.h>

#define BATCH 8
#define HH 192
#define WW 192
#define BIGF 1e10f
#define OH (HH - 10)             // 182
#define OW (WW - 10)             // 182
#define NSSIMBLK (BATCH * OH)    // 1456 ssim blocks
#define COLS_PER_BLK 3
#define NENVBLK (BATCH * WW / COLS_PER_BLK)  // 512 envelope blocks (3 cols each)

__device__ __forceinline__ float waveReduceAdd(float v) {
    #pragma unroll
    for (int o = 32; o > 0; o >>= 1) v += __shfl_down(v, o, 64);
    return v;
}

// Nearest set bit in a 192-bit mask (3x u64 words) to position x; returns |x - pos|,
// or a huge value if the mask is empty. Integer-exact. (Proven in round 7.)
__device__ __forceinline__ int nearestDist(const unsigned long long m0,
                                           const unsigned long long m1,
                                           const unsigned long long m2,
                                           int x) {
    const unsigned long long m[3] = {m0, m1, m2};
    const int wi = x >> 6, b = x & 63;
    int dL = 1 << 29;
    const unsigned long long low = m[wi] << (63 - b);   // bit b -> pos 63
    if (low) dL = __clzll(low);
    else if (wi >= 1 && m[wi - 1]) dL = b + 1 + __clzll(m[wi - 1]);
    else if (wi == 2 && m[0]) dL = b + 65 + __clzll(m[0]);
    int dR = 1 << 29;
    const unsigned long long high = m[wi] >> b;          // bit b -> pos 0
    if (high) dR = __ffsll((long long)high) - 1;
    else if (wi <= 1 && m[wi + 1]) dR = (64 - b) + __ffsll((long long)m[wi + 1]) - 1;
    else if (wi == 0 && m[2]) dR = (128 - b) + __ffsll((long long)m[2]) - 1;
    return min(dL, dR);
}

// Dispatch A: blocks [0, NENVBLK): full EDT + envelope + BCE/focal/boundary for
// 3 columns of one image (mask built in-block from tgt via ballot).
// Blocks [NENVBLK, ..): one SSIM output row each.
__global__ void mainKernel(const float* __restrict__ pred,
                           const int* __restrict__ tgt,
                           float4* __restrict__ envPart,
                           float* __restrict__ ssimPart) {
    const int x = threadIdx.x;  // 0..191

    if (blockIdx.x < NENVBLK) {
        // ================= EDT + envelope + losses =================
        const int b = blockIdx.x / (WW / COLS_PER_BLK);
        const int c0 = (blockIdx.x % (WW / COLS_PER_BLK)) * COLS_PER_BLK;

        __shared__ unsigned long long rowm[3][HH];           // per-row fg bitmask words
        __shared__ __align__(16) float scf[COLS_PER_BLK][HH];
        __shared__ __align__(16) float scb[COLS_PER_BLK][HH];
        __shared__ float red[3][3];

        // ---- build whole-image row masks (coalesced row sweep) ----
        const int wid = x >> 6;
        const int lane0 = ((x & 63) == 0);
        #pragma unroll 4
        for (int r = 0; r < HH; ++r) {
            const int t = tgt[(b * HH + r) * WW + x];
            const unsigned long long bal = __ballot(t > 0);
            if (lane0) rowm[wid][r] = bal;
        }
        __syncthreads();

        // ---- per-thread: row y = x; distances for the 3 columns ----
        const int y = x;
        const unsigned long long f0 = rowm[0][y], f1 = rowm[1][y], f2 = rowm[2][y];
        float pz[COLS_PER_BLK];
        float tfv[COLS_PER_BLK];
        #pragma unroll
        for (int cc = 0; cc < COLS_PER_BLK; ++cc) {
            const int col = c0 + cc;
            const int dfg = nearestDist(f0, f1, f2, col);
            const int dbg = nearestDist(~f0, ~f1, ~f2, col);
            const int dfc = min(dfg, 255), dbc = min(dbg, 255);
            scf[cc][y] = (dfg >= 192) ? BIGF : (float)(dfc * dfc);
            scb[cc][y] = (dbg >= 192) ? BIGF : (float)(dbc * dbc);
            // prefetch pred column value (uncoalesced; latency hidden under envelope)
            pz[cc] = pred[(b * HH + y) * WW + col];
            const unsigned long long fw = (col < 64) ? f0 : (col < 128) ? f1 : f2;
            tfv[cc] = (float)((fw >> (col & 63)) & 1ull);
        }
        __syncthreads();

        // ---- envelope + fused losses, accumulated over the 3 columns ----
        float bceA = 0.0f, focA = 0.0f, bndA = 0.0f;
        const float fy = (float)y;
        const float maxd2 = (float)((HH - 1) * (HH - 1) + (WW - 1) * (WW - 1));
        #pragma unroll
        for (int cc = 0; cc < COLS_PER_BLK; ++cc) {
            float o0 = BIGF, o1 = BIGF, o2 = BIGF, o3 = BIGF;
            float i0 = BIGF, i1 = BIGF, i2 = BIGF, i3 = BIGF;
            #pragma unroll 6
            for (int rp = 0; rp < HH; rp += 4) {
                const float4 vf = *(const float4*)&scf[cc][rp];
                const float4 vb = *(const float4*)&scb[cc][rp];
                const float e0 = fy - (float)rp;
                const float e1 = fy - (float)(rp + 1);
                const float e2 = fy - (float)(rp + 2);
                const float e3 = fy - (float)(rp + 3);
                o0 = fminf(o0, fmaf(e0, e0, vf.x)); i0 = fminf(i0, fmaf(e0, e0, vb.x));
                o1 = fminf(o1, fmaf(e1, e1, vf.y)); i1 = fminf(i1, fmaf(e1, e1, vb.y));
                o2 = fminf(o2, fmaf(e2, e2, vf.z)); i2 = fminf(i2, fmaf(e2, e2, vb.z));
                o3 = fminf(o3, fmaf(e3, e3, vf.w)); i3 = fminf(i3, fmaf(e3, e3, vb.w));
            }
            const float d2o = fminf(fminf(o0, o1), fminf(o2, o3));
            const float d2i = fminf(fminf(i0, i1), fminf(i2, i3));
            // empty-mask fallback folds into the clamp: min(1e10, maxd2) -> maxd exactly
            const float dist_out = sqrtf(fminf(d2o, maxd2));
            const float dist_in  = sqrtf(fminf(d2i, maxd2));

            const float tf = tfv[cc];
            const float phi = (tf > 0.5f) ? -dist_in : dist_out;
            const float p = 1.0f / (1.0f + __expf(-pz[cc]));

            // boundary
            const float wgt = __expf(-fabsf(phi) * 0.1f);
            bndA += wgt * fabsf(phi * p);
            // bce (log clamped at -100 like torch BCELoss)
            const float logp   = fmaxf(__logf(p), -100.0f);
            const float log1mp = fmaxf(__logf(1.0f - p), -100.0f);
            bceA += -(tf * logp + (1.0f - tf) * log1mp);
            // focal
            const float pc = fminf(fmaxf(p, 1e-6f), 1.0f - 1e-6f);
            const float pt = pc * tf + (1.0f - pc) * (1.0f - tf);
            const float at = 0.25f * tf + 0.75f * (1.0f - tf);
            const float om = 1.0f - pt;
            focA += -at * om * om * __logf(pt);
        }

        const float sb = waveReduceAdd(bceA);
        const float sf = waveReduceAdd(focA);
        const float sd = waveReduceAdd(bndA);
        if ((x & 63) == 0) { red[wid][0] = sb; red[wid][1] = sf; red[wid][2] = sd; }
        __syncthreads();
        if (x == 0) {
            envPart[blockIdx.x] = make_float4(red[0][0] + red[1][0] + red[2][0],
                                              red[0][1] + red[1][1] + red[2][1],
                                              red[0][2] + red[1][2] + red[2][2], 0.0f);
        }
    } else {
        // ================= SSIM (separable 11-tap gaussian, valid) =================
        const int blk = blockIdx.x - NENVBLK;
        const int b = blk / OH, yo = blk % OH;

        __shared__ __align__(16) float smem[5 * WW];
        __shared__ float red1[3];

        float g[11];
        {
            float s = 0.0f;
            #pragma unroll
            for (int k = 0; k < 11; ++k) {
                const float d = (float)(k - 5);
                g[k] = __expf(-d * d / 4.5f);
                s += g[k];
            }
            const float inv = 1.0f / s;
            #pragma unroll
            for (int k = 0; k < 11; ++k) g[k] *= inv;
        }

        float* sp = smem;
        float* st = smem + WW;
        float* spp = smem + 2 * WW;
        float* stt = smem + 3 * WW;
        float* spt = smem + 4 * WW;

        float ap = 0, at = 0, app = 0, att = 0, apt = 0;
        #pragma unroll
        for (int k = 0; k < 11; ++k) {
            const int row = yo + k;
            const float z = pred[(b * HH + row) * WW + x];
            const float p = 1.0f / (1.0f + __expf(-z));
            const float t = (float)tgt[(b * HH + row) * WW + x];
            const float gk = g[k];
            ap += gk * p; at += gk * t;
            app += gk * p * p; att += gk * t * t; apt += gk * p * t;
        }
        sp[x] = ap; st[x] = at; spp[x] = app; stt[x] = att; spt[x] = apt;
        __syncthreads();

        float term = 0.0f;
        if (x < OW) {
            float mx = 0, my = 0, mxx = 0, myy = 0, mxy = 0;
            #pragma unroll
            for (int k = 0; k < 11; ++k) {
                mx += g[k] * sp[x + k];  my += g[k] * st[x + k];
                mxx += g[k] * spp[x + k]; myy += g[k] * stt[x + k];
                mxy += g[k] * spt[x + k];
            }
            const float C1 = 1e-4f, C2 = 9e-4f;
            const float sx = mxx - mx * mx, sy = myy - my * my, sxy = mxy - mx * my;
            const float num = (2.0f * mx * my + C1) * (2.0f * sxy + C2);
            const float den = (mx * mx + my * my + C1) * (sx + sy + C2);
            term = num / den;
        }
        const float s = waveReduceAdd(term);
        const int wid = x >> 6;
        if ((x & 63) == 0) red1[wid] = s;
        __syncthreads();
        if (x == 0) ssimPart[blk] = red1[0] + red1[1] + red1[2];
    }
}

// Dispatch B: final reduction + combine
__global__ void reduceKernel(const float4* __restrict__ envPart,
                             const float* __restrict__ ssimPart,
                             float* __restrict__ out) {
    const int tid = threadIdx.x;  // 0..1023
    float s0 = 0, s1 = 0, s2 = 0, s3 = 0;
    for (int i = tid; i < NENVBLK; i += 1024) {
        const float4 v = envPart[i];
        s0 += v.x; s1 += v.y; s2 += v.z;
    }
    for (int i = tid; i < NSSIMBLK; i += 1024) s3 += ssimPart[i];
    s0 = waveReduceAdd(s0); s1 = waveReduceAdd(s1);
    s2 = waveReduceAdd(s2); s3 = waveReduceAdd(s3);
    __shared__ float red[16][4];
    const int wid = tid >> 6;
    if ((tid & 63) == 0) { red[wid][0] = s0; red[wid][1] = s1; red[wid][2] = s2; red[wid][3] = s3; }
    __syncthreads();
    if (tid == 0) {
        float t0 = 0, t1 = 0, t2 = 0, t3 = 0;
        #pragma unroll
        for (int w = 0; w < 16; ++w) { t0 += red[w][0]; t1 += red[w][1]; t2 += red[w][2]; t3 += red[w][3]; }
        const float N1 = (float)(BATCH * HH * WW);
        const float N2 = (float)(BATCH * OH * OW);
        out[0] = (t0 + t1 + t2) / N1 + t3 / N2;
    }
}

extern "C" void kernel_launch(void* const* d_in, const int* in_sizes, int n_in,
                              void* d_out, int out_size, void* d_ws, size_t ws_size,
                              hipStream_t stream) {
    const float* pred = (const float*)d_in[0];
    const int* tgt = (const int*)d_in[1];

    float4* envPart = (float4*)d_ws;                       // 512*16 = 8192 B
    float* ssimPart = (float*)((char*)d_ws + 8192);        // 1456*4 = 5824 B

    mainKernel<<<NENVBLK + NSSIMBLK, WW, 0, stream>>>(pred, tgt, envPart, ssimPart);
    reduceKernel<<<1, 1024, 0, stream>>>(envPart, ssimPart, (float*)d_out);
}

// Round 9
// 42.128 us; speedup vs baseline: 1.0462x; 1.0462x over previous
//
#include <hip/hip_runtime.h>
#include <math.h>

#define BATCH 8
#define HH 192
#define WW 192
#define BIGF 1e10f
#define OH (HH - 10)                               // 182
#define OW (WW - 10)                               // 182
#define SSIM_ROWS 4
#define SSIM_BPI ((OH + SSIM_ROWS - 1) / SSIM_ROWS)  // 46 blocks per image
#define NSSIMBLK (BATCH * SSIM_BPI)                // 368
#define NENVBLK (BATCH * WW)                       // 1536
#define NTOTAL (NSSIMBLK + NENVBLK)                // 1904
#define NEDTBLK (BATCH * HH)                       // 1536

__device__ __forceinline__ float waveReduceAdd(float v) {
    #pragma unroll
    for (int o = 32; o > 0; o >>= 1) v += __shfl_down(v, o, 64);
    return v;
}

// Nearest set bit in a 192-bit mask (3x u64) to position x (round-7 proven).
__device__ __forceinline__ int nearestDist(const unsigned long long m0,
                                           const unsigned long long m1,
                                           const unsigned long long m2,
                                           int x) {
    const unsigned long long m[3] = {m0, m1, m2};
    const int wi = x >> 6, b = x & 63;
    int dL = 1 << 29;
    const unsigned long long low = m[wi] << (63 - b);
    if (low) dL = __clzll(low);
    else if (wi >= 1 && m[wi - 1]) dL = b + 1 + __clzll(m[wi - 1]);
    else if (wi == 2 && m[0]) dL = b + 65 + __clzll(m[0]);
    int dR = 1 << 29;
    const unsigned long long high = m[wi] >> b;
    if (high) dR = __ffsll((long long)high) - 1;
    else if (wi <= 1 && m[wi + 1]) dR = (64 - b) + __ffsll((long long)m[wi + 1]) - 1;
    else if (wi == 0 && m[2]) dR = (128 - b) + __ffsll((long long)m[2]) - 1;
    return min(dL, dR);
}

// Dispatch A: per-row 1D EDT via ballot; packed transposed records
// colminT[b][x][r] = {f32 logit, dfg | dbg<<8 | fg<<16}. Also zeroes counter.
__global__ void edtKernel(const float* __restrict__ pred,
                          const int* __restrict__ tgt,
                          uint2* __restrict__ colminT,
                          unsigned* __restrict__ counter) {
    __shared__ unsigned long long lmask[3];
    const int x = threadIdx.x;  // 0..191
    if (blockIdx.x == 0 && x == 0)
        __hip_atomic_store(counter, 0u, __ATOMIC_RELAXED, __HIP_MEMORY_SCOPE_AGENT);
    const int b = blockIdx.x / HH, r = blockIdx.x % HH;
    const float z = pred[(b * HH + r) * WW + x];   // coalesced
    const int t = tgt[(b * HH + r) * WW + x];      // coalesced
    const int fg = (t > 0) ? 1 : 0;
    const unsigned long long bal = __ballot(fg);
    if ((x & 63) == 0) lmask[x >> 6] = bal;
    __syncthreads();
    const unsigned long long f0 = lmask[0], f1 = lmask[1], f2 = lmask[2];
    int dfg = nearestDist(f0, f1, f2, x);
    int dbg = nearestDist(~f0, ~f1, ~f2, x);
    dfg = min(dfg, 255);   // 255 = "none in row" sentinel (real d <= 191)
    dbg = min(dbg, 255);
    colminT[((size_t)b * WW + x) * HH + r] =
        make_uint2(__float_as_uint(z), (unsigned)(dfg | (dbg << 8) | (fg << 16)));
}

// Dispatch B: blocks [0,NSSIMBLK) = SSIM (4 output rows each);
// blocks [NSSIMBLK,..) = column envelope + BCE/focal/boundary.
// Per-block partials published via agent-scope atomic stores; last block
// (relaxed atomic counter after vmcnt(0) drain) reduces and writes the scalar.
__global__ void fusedKernel(const float* __restrict__ pred,
                            const int* __restrict__ tgt,
                            const uint2* __restrict__ colminT,
                            float* __restrict__ p0,
                            float* __restrict__ p1,
                            float* __restrict__ p2,
                            float* __restrict__ ssimPart,
                            unsigned* __restrict__ counter,
                            float* __restrict__ out) {
    __shared__ __align__(16) float smem[SSIM_ROWS * 5 * WW];  // 15360 B
    __shared__ float red[3][4];
    __shared__ int isLastSh;
    const int x = threadIdx.x;  // 0..191
    const int wid = x >> 6;

    if (blockIdx.x < NSSIMBLK) {
        // ================= SSIM: 4 output rows per block =================
        const int blk = blockIdx.x;
        const int b = blk / SSIM_BPI;
        const int r0 = (blk % SSIM_BPI) * SSIM_ROWS;

        float g[11];
        {
            float s = 0.0f;
            #pragma unroll
            for (int k = 0; k < 11; ++k) {
                const float d = (float)(k - 5);
                g[k] = __expf(-d * d / 4.5f);
                s += g[k];
            }
            const float inv = 1.0f / s;
            #pragma unroll
            for (int k = 0; k < 11; ++k) g[k] *= inv;
        }

        float acc[SSIM_ROWS][5];
        #pragma unroll
        for (int o = 0; o < SSIM_ROWS; ++o)
            #pragma unroll
            for (int s = 0; s < 5; ++s) acc[o][s] = 0.0f;

        #pragma unroll
        for (int j = 0; j < SSIM_ROWS + 10; ++j) {
            const int row = r0 + j;
            float p = 0.0f, t = 0.0f;
            if (row < HH) {
                const float z = pred[(b * HH + row) * WW + x];
                p = 1.0f / (1.0f + __expf(-z));
                t = (float)tgt[(b * HH + row) * WW + x];
            }
            const float pp = p * p, tt = t * t, pt = p * t;
            #pragma unroll
            for (int o = 0; o < SSIM_ROWS; ++o) {
                const int k = j - o;
                if (k >= 0 && k <= 10) {
                    const float gk = g[k];
                    acc[o][0] += gk * p;  acc[o][1] += gk * t;
                    acc[o][2] += gk * pp; acc[o][3] += gk * tt; acc[o][4] += gk * pt;
                }
            }
        }
        #pragma unroll
        for (int o = 0; o < SSIM_ROWS; ++o)
            #pragma unroll
            for (int s = 0; s < 5; ++s) smem[(o * 5 + s) * WW + x] = acc[o][s];
        __syncthreads();

        float term = 0.0f;
        if (x < OW) {
            #pragma unroll
            for (int o = 0; o < SSIM_ROWS; ++o) {
                if (r0 + o < OH) {   // uniform per block
                    float mx = 0, my = 0, mxx = 0, myy = 0, mxy = 0;
                    #pragma unroll
                    for (int k = 0; k < 11; ++k) {
                        mx  += g[k] * smem[(o * 5 + 0) * WW + x + k];
                        my  += g[k] * smem[(o * 5 + 1) * WW + x + k];
                        mxx += g[k] * smem[(o * 5 + 2) * WW + x + k];
                        myy += g[k] * smem[(o * 5 + 3) * WW + x + k];
                        mxy += g[k] * smem[(o * 5 + 4) * WW + x + k];
                    }
                    const float C1 = 1e-4f, C2 = 9e-4f;
                    const float sx = mxx - mx * mx, sy = myy - my * my, sxy = mxy - mx * my;
                    const float num = (2.0f * mx * my + C1) * (2.0f * sxy + C2);
                    const float den = (mx * mx + my * my + C1) * (sx + sy + C2);
                    term += num / den;
                }
            }
        }
        const float s = waveReduceAdd(term);
        if ((x & 63) == 0) red[wid][0] = s;
        __syncthreads();
        if (x == 0)
            __hip_atomic_store(&ssimPart[blk], red[0][0] + red[1][0] + red[2][0],
                               __ATOMIC_RELAXED, __HIP_MEMORY_SCOPE_AGENT);
    } else {
        // ================= envelope + fused losses (round-7 proven) =================
        const int ebid = blockIdx.x - NSSIMBLK;
        const int b = ebid / WW, cx = ebid % WW;
        const int y = x;

        float2* scfb = (float2*)smem;
        const uint2 v = colminT[((size_t)b * WW + cx) * HH + y];  // coalesced 8B/lane
        const int dfg = v.y & 255, dbg = (v.y >> 8) & 255;
        scfb[y] = make_float2(dfg == 255 ? BIGF : (float)(dfg * dfg),
                              dbg == 255 ? BIGF : (float)(dbg * dbg));
        __syncthreads();

        float o0 = BIGF, o1 = BIGF, o2 = BIGF, o3 = BIGF;
        float i0 = BIGF, i1 = BIGF, i2 = BIGF, i3 = BIGF;
        const float fy = (float)y;
        #pragma unroll 6
        for (int rp = 0; rp < HH; rp += 4) {
            const float4 v0 = *(const float4*)&scfb[rp];
            const float4 v1 = *(const float4*)&scfb[rp + 2];
            const float e0 = fy - (float)rp;
            const float e1 = fy - (float)(rp + 1);
            const float e2 = fy - (float)(rp + 2);
            const float e3 = fy - (float)(rp + 3);
            o0 = fminf(o0, fmaf(e0, e0, v0.x)); i0 = fminf(i0, fmaf(e0, e0, v0.y));
            o1 = fminf(o1, fmaf(e1, e1, v0.z)); i1 = fminf(i1, fmaf(e1, e1, v0.w));
            o2 = fminf(o2, fmaf(e2, e2, v1.x)); i2 = fminf(i2, fmaf(e2, e2, v1.y));
            o3 = fminf(o3, fmaf(e3, e3, v1.z)); i3 = fminf(i3, fmaf(e3, e3, v1.w));
        }
        const float d2o = fminf(fminf(o0, o1), fminf(o2, o3));
        const float d2i = fminf(fminf(i0, i1), fminf(i2, i3));

        const float maxd2 = (float)((HH - 1) * (HH - 1) + (WW - 1) * (WW - 1));
        const float dist_out = sqrtf(fminf(d2o, maxd2));
        const float dist_in  = sqrtf(fminf(d2i, maxd2));

        const float tf = (float)((v.y >> 16) & 255);
        const float phi = (tf > 0.5f) ? -dist_in : dist_out;
        const float z = __uint_as_float(v.x);
        const float p = 1.0f / (1.0f + __expf(-z));

        const float wgt = __expf(-fabsf(phi) * 0.1f);
        const float bnd = wgt * fabsf(phi * p);

        const float logp   = fmaxf(__logf(p), -100.0f);
        const float log1mp = fmaxf(__logf(1.0f - p), -100.0f);
        const float bce = -(tf * logp + (1.0f - tf) * log1mp);

        const float pc = fminf(fmaxf(p, 1e-6f), 1.0f - 1e-6f);
        const float pt = pc * tf + (1.0f - pc) * (1.0f - tf);
        const float at = 0.25f * tf + 0.75f * (1.0f - tf);
        const float om = 1.0f - pt;
        const float focal = -at * om * om * __logf(pt);

        const float sb = waveReduceAdd(bce);
        const float sf = waveReduceAdd(focal);
        const float sd = waveReduceAdd(bnd);
        if ((x & 63) == 0) { red[wid][0] = sb; red[wid][1] = sf; red[wid][2] = sd; }
        __syncthreads();
        if (x == 0) {
            __hip_atomic_store(&p0[ebid], red[0][0] + red[1][0] + red[2][0],
                               __ATOMIC_RELAXED, __HIP_MEMORY_SCOPE_AGENT);
            __hip_atomic_store(&p1[ebid], red[0][1] + red[1][1] + red[2][1],
                               __ATOMIC_RELAXED, __HIP_MEMORY_SCOPE_AGENT);
            __hip_atomic_store(&p2[ebid], red[0][2] + red[1][2] + red[2][2],
                               __ATOMIC_RELAXED, __HIP_MEMORY_SCOPE_AGENT);
        }
    }

    // ---- publication + last-block election (no fences, no cache flushes) ----
    if (x == 0) {
        asm volatile("s_waitcnt vmcnt(0)" ::: "memory");  // drain write-through stores
        const unsigned old = __hip_atomic_fetch_add(counter, 1u, __ATOMIC_RELAXED,
                                                    __HIP_MEMORY_SCOPE_AGENT);
        isLastSh = (old == NTOTAL - 1) ? 1 : 0;
    }
    __syncthreads();

    if (isLastSh) {
        float s0 = 0, s1 = 0, s2 = 0, s3 = 0;
        for (int i = x; i < NENVBLK; i += WW) {
            s0 += __hip_atomic_load(&p0[i], __ATOMIC_RELAXED, __HIP_MEMORY_SCOPE_AGENT);
            s1 += __hip_atomic_load(&p1[i], __ATOMIC_RELAXED, __HIP_MEMORY_SCOPE_AGENT);
            s2 += __hip_atomic_load(&p2[i], __ATOMIC_RELAXED, __HIP_MEMORY_SCOPE_AGENT);
        }
        for (int i = x; i < NSSIMBLK; i += WW)
            s3 += __hip_atomic_load(&ssimPart[i], __ATOMIC_RELAXED, __HIP_MEMORY_SCOPE_AGENT);
        s0 = waveReduceAdd(s0); s1 = waveReduceAdd(s1);
        s2 = waveReduceAdd(s2); s3 = waveReduceAdd(s3);
        __syncthreads();  // red[] reuse
        if ((x & 63) == 0) { red[wid][0] = s0; red[wid][1] = s1; red[wid][2] = s2; red[wid][3] = s3; }
        __syncthreads();
        if (x == 0) {
            float t0 = 0, t1 = 0, t2 = 0, t3 = 0;
            #pragma unroll
            for (int w = 0; w < 3; ++w) { t0 += red[w][0]; t1 += red[w][1]; t2 += red[w][2]; t3 += red[w][3]; }
            const float N1 = (float)(BATCH * HH * WW);
            const float N2 = (float)(BATCH * OH * OW);
            out[0] = (t0 + t1 + t2) / N1 + t3 / N2;
        }
    }
}

extern "C" void kernel_launch(void* const* d_in, const int* in_sizes, int n_in,
                              void* d_out, int out_size, void* d_ws, size_t ws_size,
                              hipStream_t stream) {
    const float* pred = (const float*)d_in[0];
    const int* tgt = (const int*)d_in[1];

    unsigned* counter = (unsigned*)d_ws;                    // 4 B (padded)
    float* p0 = (float*)((char*)d_ws + 64);                 // 1536 floats
    float* p1 = p0 + NENVBLK;
    float* p2 = p1 + NENVBLK;
    float* ssimPart = p2 + NENVBLK;                         // 368 floats
    uint2* colminT = (uint2*)((char*)d_ws + 32768);         // 8*192*192*8 = 2359296 B

    edtKernel<<<NEDTBLK, WW, 0, stream>>>(pred, tgt, colminT, counter);
    fusedKernel<<<NTOTAL, WW, 0, stream>>>(pred, tgt, colminT, p0, p1, p2,
                                           ssimPart, counter, (float*)d_out);
}